// Round 1
// 3200.779 us; speedup vs baseline: 2.4174x; 2.4174x over previous
//
#include <hip/hip_runtime.h>
#include <hip/hip_bf16.h>

#define Hh 1024
#define INs 512
#define Bb 256
#define Tt 256
#define DT_ 0.1f
#define Z_MIN_ 0.001f
#define Z_MAX_ 0.1f
#define KW (Hh + INs)   // 1536 combined K
#define NB 256          // persistent grid = 1 block per CU

typedef __attribute__((ext_vector_type(8))) short short8;
typedef __attribute__((ext_vector_type(4))) float f32x4;

__device__ __forceinline__ float sigmoidf_(float x) {
    return 1.0f / (1.0f + __expf(-x));
}

__device__ __forceinline__ unsigned short f2bf(float f) {
    union { float f; unsigned u; } v; v.f = f;
    unsigned r = v.u + 0x7FFFu + ((v.u >> 16) & 1u);  // RNE
    return (unsigned short)(r >> 16);
}

// ---- build W1=[K|p_z], W2=[w_r|p_r] as bf16 row-major 1024 x 1536 ----
__global__ __launch_bounds__(256) void build_weights(
    const float* __restrict__ Km, const float* __restrict__ p_z,
    const float* __restrict__ w_r, const float* __restrict__ p_r,
    unsigned short* __restrict__ W1, unsigned short* __restrict__ W2) {
    int idx = blockIdx.x * 256 + threadIdx.x;
    int h = idx / KW, k = idx % KW;
    float a = (k < Hh) ? Km[h * Hh + k] : p_z[h * INs + (k - Hh)];
    float b = (k < Hh) ? w_r[h * Hh + k] : p_r[h * INs + (k - Hh)];
    W1[idx] = f2bf(a);
    W2[idx] = f2bf(b);
}

// ---- x (T, IN, B) fp32 -> xT (T, B, IN) bf16 ----
__global__ __launch_bounds__(256) void transpose_x(
    const float* __restrict__ x, unsigned short* __restrict__ xT) {
    __shared__ unsigned short tile[64][65];
    int t = blockIdx.z;
    int i0 = blockIdx.y * 64;
    int b0 = blockIdx.x * 64;
    int c = threadIdx.x & 63, rbase = threadIdx.x >> 6;
    const float* xp = x + (size_t)t * INs * Bb;
#pragma unroll
    for (int r = 0; r < 16; ++r) {
        int row = r * 4 + rbase;
        tile[row][c] = f2bf(xp[(size_t)(i0 + row) * Bb + (b0 + c)]);
    }
    __syncthreads();
    unsigned short* op = xT + (size_t)t * Bb * INs;
#pragma unroll
    for (int r = 0; r < 16; ++r) {
        int brow = r * 4 + rbase;
        op[(size_t)(b0 + brow) * INs + (i0 + c)] = tile[c][brow];
    }
}

// ---- gate-rate constants (H each) ----
__global__ __launch_bounds__(256) void precomp_gates(
    const float* __restrict__ c_x, const float* __restrict__ c_u,
    const float* __restrict__ c_U,
    float* __restrict__ zxv, float* __restrict__ zuv, float* __restrict__ Ucv) {
    int h = blockIdx.x * 256 + threadIdx.x;
    zxv[h] = Z_MIN_ + (Z_MAX_ - Z_MIN_) * sigmoidf_(c_x[h]);
    zuv[h] = Z_MIN_ + (Z_MAX_ - Z_MIN_) * sigmoidf_(c_u[h]);
    Ucv[h] = 0.9f * sigmoidf_(c_U[h]);
}

// ---- initial R_0, M_0 (B,H) bf16 ; also zero the 8 per-colg barrier words ----
__global__ __launch_bounds__(256) void init_state(
    const float* __restrict__ zxv, const float* __restrict__ zuv,
    const float* __restrict__ Ucv,
    unsigned short* __restrict__ R0, unsigned short* __restrict__ M0,
    unsigned* __restrict__ bar) {
    int idx = blockIdx.x * 256 + threadIdx.x;           // over B*H
    if (idx < 8) bar[idx * 32] = 0;                     // 8 counters, 128B apart
    int h = idx & (Hh - 1);
    float zx = zxv[h], zu = zuv[h], Uc = Ucv[h];
    const float r = 0.5f;                                // sigmoid(0)
    float Xn = zx + (1.0f - zx) - 0.45f;                 // X0=1,U0=0.9
    float Un = Uc * zu + (1.0f - zu) * 0.9f + Uc * 0.05f;
    Un = fminf(fmaxf(Un, Uc), 1.0f);
    R0[idx] = f2bf(r);
    M0[idx] = f2bf(Un * Xn * r);
}

// x-projection partial: chunks 16..23 of this wave's pinned weights
__device__ __forceinline__ void xproj(
    const unsigned short* xp0, const unsigned short* xp1,
    const short8* wf1, const short8* wf2,
    f32x4& a10, f32x4& a11, f32x4& a20, f32x4& a21) {
    f32x4 z = {0.0f, 0.0f, 0.0f, 0.0f};
    a10 = z; a11 = z; a20 = z; a21 = z;
#pragma unroll
    for (int c = 16; c < 24; ++c) {
        short8 bx0 = *(const short8*)(xp0 + (c - 16) * 32);
        short8 bx1 = *(const short8*)(xp1 + (c - 16) * 32);
        a10 = __builtin_amdgcn_mfma_f32_16x16x32_bf16(wf1[c], bx0, a10, 0, 0, 0);
        a11 = __builtin_amdgcn_mfma_f32_16x16x32_bf16(wf1[c], bx1, a11, 0, 0, 0);
        a20 = __builtin_amdgcn_mfma_f32_16x16x32_bf16(wf2[c], bx0, a20, 0, 0, 0);
        a21 = __builtin_amdgcn_mfma_f32_16x16x32_bf16(wf2[c], bx1, a21, 0, 0, 0);
    }
}

// ---- persistent kernel: all 256 timesteps ----
// 256 WGs x 256 thr; 1 block/CU. WG tile 32 rows x 32 cols; waves rh x kh.
// K split: kh owns recurrent [kh*512, kh*512+512) + x-proj [kh*256, kh*256+256).
//
// SYNC DESIGN (this revision): the R/M state exchange is entirely intra-XCD:
// columns [colg*32, colg*32+32) are written and read only by blocks with
// blockIdx % 8 == colg, which all land on the same XCD (round-robin dispatch).
// Writer stores drain to that XCD's L2 at the pre-barrier vmcnt(0) of
// __syncthreads(); readers share the same L2. Therefore NO agent-scope fences
// (buffer_wbl2/buffer_inv sc1 — full L2 walks, the previous 29 us/step cost)
// are needed. Per step we only need:
//   - a per-colg monotonic arrival counter (relaxed agent atomics -> no
//     implicit cache maintenance, atomics are IC-coherent),
//   - a per-CU L1-only invalidate (buffer_inv sc0) after the wait, since the
//     CU's L1 may hold stale R/M lines cached from step t-1.
// WAR safety across the 2-deep state buffers holds because a block reaches
// step t+1's stores only after cnt >= 32*(t+1), i.e. after every peer has
// fully consumed buf[t&1].
__global__ __launch_bounds__(256, 1) void persist_kernel(
    const unsigned short* __restrict__ W1, const unsigned short* __restrict__ W2,
    const unsigned short* __restrict__ xT,
    unsigned short* __restrict__ Rb0, unsigned short* __restrict__ Rb1,
    unsigned short* __restrict__ Mb0, unsigned short* __restrict__ Mb1,
    float* __restrict__ out,
    const float* __restrict__ g_z, const float* __restrict__ b_r,
    const float* __restrict__ zxv, const float* __restrict__ zuv,
    const float* __restrict__ Ucv, unsigned* __restrict__ bar) {

    const int tid = threadIdx.x;
    const int wave = tid >> 6, lane = tid & 63;
    const int m = lane & 15, q = lane >> 4;
    const int rh = wave >> 1;          // 0..1: row half
    const int kh = wave & 1;           // 0..1: K half
    const int rowg = blockIdx.x >> 3;  // 32 row groups (32 rows each)
    const int colg = blockIdx.x & 7;   // 8 col groups (32 cols) — XCD-aligned

    unsigned* cnt = bar + (unsigned)colg * 32;   // per-colg counter, 128B apart

    const int arow = rowg * 32 + rh * 16 + m;
    const int krec = kh * 512;                 // recurrent K base
    const int kx = kh * 256;                   // x-proj K base (within IN)
    const int bcol0 = colg * 32 + m;
    const int bcol1 = colg * 32 + 16 + m;

    // ---- pin weights in registers: 16 recurrent + 8 x-proj chunks, x2 ----
    short8 wf1[24], wf2[24];
    {
        const unsigned short* w1r = W1 + (size_t)arow * KW + krec + q * 8;
        const unsigned short* w2r = W2 + (size_t)arow * KW + krec + q * 8;
#pragma unroll
        for (int c = 0; c < 16; ++c) {
            wf1[c] = *(const short8*)(w1r + c * 32);
            wf2[c] = *(const short8*)(w2r + c * 32);
        }
        const unsigned short* w1x = W1 + (size_t)arow * KW + Hh + kx + q * 8;
        const unsigned short* w2x = W2 + (size_t)arow * KW + Hh + kx + q * 8;
#pragma unroll
        for (int c = 16; c < 24; ++c) {
            wf1[c] = *(const short8*)(w1x + (c - 16) * 32);
            wf2[c] = *(const short8*)(w2x + (c - 16) * 32);
        }
    }

    // ---- epilogue constants + persistent per-lane state (kh==0 owns it) ----
    const int h04 = rowg * 32 + rh * 16 + q * 4;
    f32x4 zx4 = *(const f32x4*)(zxv + h04);
    f32x4 zu4 = *(const f32x4*)(zuv + h04);
    f32x4 Uc4 = *(const f32x4*)(Ucv + h04);
    f32x4 gz4 = *(const f32x4*)(g_z + h04);
    f32x4 br4 = *(const f32x4*)(b_r + h04);

    f32x4 vr[2], Xr[2], Ur[2];
#pragma unroll
    for (int nt = 0; nt < 2; ++nt)
#pragma unroll
        for (int e = 0; e < 4; ++e) {
            vr[nt][e] = 0.0f;
            float Xn = zx4[e] + (1.0f - zx4[e]) - 0.45f;
            float Un = Uc4[e] * zu4[e] + (1.0f - zu4[e]) * 0.9f + Uc4[e] * 0.05f;
            Un = fminf(fmaxf(Un, Uc4[e]), 1.0f);
            Xr[nt][e] = Xn; Ur[nt][e] = Un;
        }

    __shared__ f32x4 red[2][4][64];   // [rh][acc][lane]

    // pre-loop: x-projection partials for t=0
    f32x4 xa10, xa11, xa20, xa21;
    xproj(xT + (size_t)bcol0 * INs + kx + q * 8,
          xT + (size_t)bcol1 * INs + kx + q * 8, wf1, wf2,
          xa10, xa11, xa20, xa21);

    for (int t = 0; t < Tt; ++t) {
        const unsigned short* Rt = (t & 1) ? Rb1 : Rb0;
        const unsigned short* Mt = (t & 1) ? Mb1 : Mb0;
        unsigned short* Rn = (t & 1) ? Rb0 : Rb1;
        unsigned short* Mn = (t & 1) ? Mb0 : Mb1;

        f32x4 g10 = xa10, g11 = xa11, g20 = xa20, g21 = xa21;

        const unsigned short* rp0 = Rt + (size_t)bcol0 * Hh + krec + q * 8;
        const unsigned short* rp1 = Rt + (size_t)bcol1 * Hh + krec + q * 8;
        const unsigned short* mp0 = Mt + (size_t)bcol0 * Hh + krec + q * 8;
        const unsigned short* mp1 = Mt + (size_t)bcol1 * Hh + krec + q * 8;

#pragma unroll
        for (int c = 0; c < 16; ++c) {
            short8 bR0 = *(const short8*)(rp0 + c * 32);
            short8 bR1 = *(const short8*)(rp1 + c * 32);
            short8 bM0 = *(const short8*)(mp0 + c * 32);
            short8 bM1 = *(const short8*)(mp1 + c * 32);
            g10 = __builtin_amdgcn_mfma_f32_16x16x32_bf16(wf1[c], bR0, g10, 0, 0, 0);
            g11 = __builtin_amdgcn_mfma_f32_16x16x32_bf16(wf1[c], bR1, g11, 0, 0, 0);
            g20 = __builtin_amdgcn_mfma_f32_16x16x32_bf16(wf2[c], bM0, g20, 0, 0, 0);
            g21 = __builtin_amdgcn_mfma_f32_16x16x32_bf16(wf2[c], bM1, g21, 0, 0, 0);
        }

        if (kh == 1) {
            red[rh][0][lane] = g10;
            red[rh][1][lane] = g11;
            red[rh][2][lane] = g20;
            red[rh][3][lane] = g21;
        }
        __syncthreads();

        if (kh == 0) {
            g10 += red[rh][0][lane];
            g11 += red[rh][1][lane];
            g20 += red[rh][2][lane];
            g21 += red[rh][3][lane];

#pragma unroll
            for (int nt = 0; nt < 2; ++nt) {
                f32x4 g1 = nt ? g11 : g10;
                f32x4 g2 = nt ? g21 : g20;
                const int bcol = nt ? bcol1 : bcol0;
                const size_t base = (size_t)bcol * Hh + h04;
                f32x4 vv;
                ushort4 rq, mq;
#pragma unroll
                for (int e = 0; e < 4; ++e) {
                    float z = DT_ * sigmoidf_(g1[e] + gz4[e]);
                    float vnew = (1.0f - z) * vr[nt][e] + DT_ * (g2[e] + br4[e]);
                    vr[nt][e] = vnew;
                    vv[e] = vnew;
                    float r = sigmoidf_(vnew);
                    float Xs = Xr[nt][e], Us = Ur[nt][e];
                    float Xn = zx4[e] + (1.0f - zx4[e]) * Xs - Us * Xs * r;
                    float Un = Uc4[e] * zu4[e] + (1.0f - zu4[e]) * Us
                             + Uc4[e] * (1.0f - Us) * r;
                    Un = fminf(fmaxf(Un, Uc4[e]), 1.0f);
                    Xr[nt][e] = Xn; Ur[nt][e] = Un;
                    unsigned short rb = f2bf(r), mb = f2bf(Un * Xn * r);
                    if (e == 0) { rq.x = rb; mq.x = mb; }
                    else if (e == 1) { rq.y = rb; mq.y = mb; }
                    else if (e == 2) { rq.z = rb; mq.z = mb; }
                    else { rq.w = rb; mq.w = mb; }
                }
                *(f32x4*)(out + (size_t)t * Bb * Hh + base) = vv;
                *(ushort4*)(Rn + base) = rq;
                *(ushort4*)(Mn + base) = mq;
            }
        }
        __syncthreads();   // every wave drains vmcnt(0) here -> all state
                           // stores of this block are visible in this XCD's L2

        if (t + 1 < Tt) {
            // ---- arrive: relaxed monotonic add, no cache maintenance ----
            if (tid == 0)
                __hip_atomic_fetch_add(cnt, 1u, __ATOMIC_RELAXED,
                                       __HIP_MEMORY_SCOPE_AGENT);
            // ---- overlap: x-projection for step t+1 (xT is read-only) ----
            const unsigned short* xn = xT + (size_t)(t + 1) * Bb * INs;
            xproj(xn + (size_t)bcol0 * INs + kx + q * 8,
                  xn + (size_t)bcol1 * INs + kx + q * 8, wf1, wf2,
                  xa10, xa11, xa20, xa21);
            // ---- wait: all 32 same-colg peers (same XCD) arrived ----
            if (tid == 0) {
                const unsigned tgt = (unsigned)(t + 1) * 32u;
                while (__hip_atomic_load(cnt, __ATOMIC_RELAXED,
                                         __HIP_MEMORY_SCOPE_AGENT) < tgt)
                    __builtin_amdgcn_s_sleep(1);
                // L1-only flash invalidate: peers' fresh R/M is in our shared
                // L2; drop any stale per-CU L1 lines from step t-1. Cheap —
                // NOT the full-L2 walk (buffer_inv sc1 / buffer_wbl2) that the
                // old agent-scope __threadfence() pair emitted.
                asm volatile("buffer_inv sc0" ::: "memory");
            }
            __syncthreads();
        }
    }
}

extern "C" void kernel_launch(void* const* d_in, const int* in_sizes, int n_in,
                              void* d_out, int out_size, void* d_ws, size_t ws_size,
                              hipStream_t stream) {
    const float* x   = (const float*)d_in[0];
    const float* c_x = (const float*)d_in[1];
    const float* c_u = (const float*)d_in[2];
    const float* c_U = (const float*)d_in[3];
    const float* w_r = (const float*)d_in[4];
    const float* p_r = (const float*)d_in[5];
    const float* b_r = (const float*)d_in[6];
    const float* g_z = (const float*)d_in[7];
    const float* Km  = (const float*)d_in[8];
    const float* p_z = (const float*)d_in[9];
    float* out = (float*)d_out;

    char* w = (char*)d_ws;
    unsigned short* W1 = (unsigned short*)w;   w += (size_t)Hh * KW * 2;
    unsigned short* W2 = (unsigned short*)w;   w += (size_t)Hh * KW * 2;
    unsigned short* xT = (unsigned short*)w;   w += (size_t)Tt * Bb * INs * 2;
    unsigned short* Rb0 = (unsigned short*)w;  w += (size_t)Bb * Hh * 2;
    unsigned short* Rb1 = (unsigned short*)w;  w += (size_t)Bb * Hh * 2;
    unsigned short* Mb0 = (unsigned short*)w;  w += (size_t)Bb * Hh * 2;
    unsigned short* Mb1 = (unsigned short*)w;  w += (size_t)Bb * Hh * 2;
    float* zxv = (float*)w;                    w += 4096;
    float* zuv = (float*)w;                    w += 4096;
    float* Ucv = (float*)w;                    w += 4096;
    unsigned* bar = (unsigned*)w;              w += 4096;

    build_weights<<<(Hh * KW) / 256, 256, 0, stream>>>(Km, p_z, w_r, p_r, W1, W2);
    transpose_x<<<dim3(Bb / 64, INs / 64, Tt), 256, 0, stream>>>(x, xT);
    precomp_gates<<<Hh / 256, 256, 0, stream>>>(c_x, c_u, c_U, zxv, zuv, Ucv);
    init_state<<<(Bb * Hh) / 256, 256, 0, stream>>>(zxv, zuv, Ucv, Rb0, Mb0, bar);

    persist_kernel<<<NB, 256, 0, stream>>>(
        W1, W2, xT, Rb0, Rb1, Mb0, Mb1, out,
        g_z, b_r, zxv, zuv, Ucv, bar);
}

// Round 3
// 2015.547 us; speedup vs baseline: 3.8389x; 1.5880x over previous
//
#include <hip/hip_runtime.h>
#include <hip/hip_bf16.h>

#define Hh 1024
#define INs 512
#define Bb 256
#define Tt 256
#define DT_ 0.1f
#define Z_MIN_ 0.001f
#define Z_MAX_ 0.1f
#define KW (Hh + INs)   // 1536 combined K
#define NB 256          // persistent grid = 1 block per CU

typedef __attribute__((ext_vector_type(8))) short short8;
typedef __attribute__((ext_vector_type(4))) float f32x4;

__device__ __forceinline__ float sigmoidf_(float x) {
    return 1.0f / (1.0f + __expf(-x));
}

__device__ __forceinline__ unsigned short f2bf(float f) {
    union { float f; unsigned u; } v; v.f = f;
    unsigned r = v.u + 0x7FFFu + ((v.u >> 16) & 1u);  // RNE
    return (unsigned short)(r >> 16);
}

// ---- build W1=[K|p_z], W2=[w_r|p_r] as bf16 row-major 1024 x 1536 ----
__global__ __launch_bounds__(256) void build_weights(
    const float* __restrict__ Km, const float* __restrict__ p_z,
    const float* __restrict__ w_r, const float* __restrict__ p_r,
    unsigned short* __restrict__ W1, unsigned short* __restrict__ W2) {
    int idx = blockIdx.x * 256 + threadIdx.x;
    int h = idx / KW, k = idx % KW;
    float a = (k < Hh) ? Km[h * Hh + k] : p_z[h * INs + (k - Hh)];
    float b = (k < Hh) ? w_r[h * Hh + k] : p_r[h * INs + (k - Hh)];
    W1[idx] = f2bf(a);
    W2[idx] = f2bf(b);
}

// ---- x (T, IN, B) fp32 -> xT (T, B, IN) bf16 ----
__global__ __launch_bounds__(256) void transpose_x(
    const float* __restrict__ x, unsigned short* __restrict__ xT) {
    __shared__ unsigned short tile[64][65];
    int t = blockIdx.z;
    int i0 = blockIdx.y * 64;
    int b0 = blockIdx.x * 64;
    int c = threadIdx.x & 63, rbase = threadIdx.x >> 6;
    const float* xp = x + (size_t)t * INs * Bb;
#pragma unroll
    for (int r = 0; r < 16; ++r) {
        int row = r * 4 + rbase;
        tile[row][c] = f2bf(xp[(size_t)(i0 + row) * Bb + (b0 + c)]);
    }
    __syncthreads();
    unsigned short* op = xT + (size_t)t * Bb * INs;
#pragma unroll
    for (int r = 0; r < 16; ++r) {
        int brow = r * 4 + rbase;
        op[(size_t)(b0 + brow) * INs + (i0 + c)] = tile[c][brow];
    }
}

// ---- gate-rate constants (H each) ----
__global__ __launch_bounds__(256) void precomp_gates(
    const float* __restrict__ c_x, const float* __restrict__ c_u,
    const float* __restrict__ c_U,
    float* __restrict__ zxv, float* __restrict__ zuv, float* __restrict__ Ucv) {
    int h = blockIdx.x * 256 + threadIdx.x;
    zxv[h] = Z_MIN_ + (Z_MAX_ - Z_MIN_) * sigmoidf_(c_x[h]);
    zuv[h] = Z_MIN_ + (Z_MAX_ - Z_MIN_) * sigmoidf_(c_u[h]);
    Ucv[h] = 0.9f * sigmoidf_(c_U[h]);
}

// ---- initial R_0, M_0 (B,H) bf16 ; also zero the 8 per-colg barrier words ----
__global__ __launch_bounds__(256) void init_state(
    const float* __restrict__ zxv, const float* __restrict__ zuv,
    const float* __restrict__ Ucv,
    unsigned short* __restrict__ R0, unsigned short* __restrict__ M0,
    unsigned* __restrict__ bar) {
    int idx = blockIdx.x * 256 + threadIdx.x;           // over B*H
    if (idx < 8) bar[idx * 32] = 0;                     // 8 counters, 128B apart
    int h = idx & (Hh - 1);
    float zx = zxv[h], zu = zuv[h], Uc = Ucv[h];
    const float r = 0.5f;                                // sigmoid(0)
    float Xn = zx + (1.0f - zx) - 0.45f;                 // X0=1,U0=0.9
    float Un = Uc * zu + (1.0f - zu) * 0.9f + Uc * 0.05f;
    Un = fminf(fmaxf(Un, Uc), 1.0f);
    R0[idx] = f2bf(r);
    M0[idx] = f2bf(Un * Xn * r);
}

// ---- persistent kernel: all 256 timesteps ----
// (R3 = R2 resubmit; R2 bench was an infra failure — container died on
// acquire/push, no pass/fail verdict, no profile.)
//
// R2 restructure: waves are a 4-way K-split (kq = wave, each owns recurrent
// K-quarter [kq*256,+256) + x-quarter [kq*128,+128), covering ALL 32 rows via
// 2 A-fragment rowsets). This removes the rh-duplicated B-operand loads of
// the old (rh x kh) layout — per-step per-XCD L2 state traffic halves.
// x-operands for step t+1 are prefetched into registers at the top of step t
// (8 x short8), so the cold-HBM xT fetch hides under the recurrent phase and
// step t's x-projection runs as register-only MFMAs with zero load stalls.
// Epilogue is spread across all 4 waves (one 16x16 output quadrant each).
//
// SYNC (unchanged from R1, verified): state exchange is intra-XCD
// (blockIdx%8 == colg == XCD); stores drain to the shared L2 at the
// pre-barrier vmcnt(0); per-colg monotonic counter (relaxed agent atomics) +
// per-CU L1-only invalidate (buffer_inv sc0). No agent-scope L2 walks.
__global__ __launch_bounds__(256, 1) void persist_kernel(
    const unsigned short* __restrict__ W1, const unsigned short* __restrict__ W2,
    const unsigned short* __restrict__ xT,
    unsigned short* __restrict__ Rb0, unsigned short* __restrict__ Rb1,
    unsigned short* __restrict__ Mb0, unsigned short* __restrict__ Mb1,
    float* __restrict__ out,
    const float* __restrict__ g_z, const float* __restrict__ b_r,
    const float* __restrict__ zxv, const float* __restrict__ zuv,
    const float* __restrict__ Ucv, unsigned* __restrict__ bar) {

    const int tid = threadIdx.x;
    const int wave = tid >> 6, lane = tid & 63;
    const int m = lane & 15, q = lane >> 4;
    const int kq = wave;               // 0..3: K quarter
    const int rowg = blockIdx.x >> 3;  // 32 row groups (32 rows each)
    const int colg = blockIdx.x & 7;   // 8 col groups (32 cols) — XCD-aligned

    unsigned* cnt = bar + (unsigned)colg * 32;   // per-colg counter, 128B apart

    const int krec = kq * 256;                 // recurrent K base (quarter)
    const int kx = kq * 128;                   // x-proj K base (quarter of IN)
    const int bcol0 = colg * 32 + m;
    const int bcol1 = bcol0 + 16;

    // ---- pin weights: 2 rowsets x (8 rec + 4 x) chunks x 2 matrices ----
    short8 wf1[2][12], wf2[2][12];
#pragma unroll
    for (int rs = 0; rs < 2; ++rs) {
        const int arow = rowg * 32 + rs * 16 + m;
        const unsigned short* w1r = W1 + (size_t)arow * KW + krec + q * 8;
        const unsigned short* w2r = W2 + (size_t)arow * KW + krec + q * 8;
#pragma unroll
        for (int c = 0; c < 8; ++c) {
            wf1[rs][c] = *(const short8*)(w1r + c * 32);
            wf2[rs][c] = *(const short8*)(w2r + c * 32);
        }
        const unsigned short* w1x = W1 + (size_t)arow * KW + Hh + kx + q * 8;
        const unsigned short* w2x = W2 + (size_t)arow * KW + Hh + kx + q * 8;
#pragma unroll
        for (int c = 0; c < 4; ++c) {
            wf1[rs][8 + c] = *(const short8*)(w1x + c * 32);
            wf2[rs][8 + c] = *(const short8*)(w2x + c * 32);
        }
    }

    // ---- this wave's epilogue quadrant: rows rs_e*16.., cols ch_e*16.. ----
    const int rs_e = wave >> 1, ch_e = wave & 1;
    const int h04 = rowg * 32 + rs_e * 16 + q * 4;
    const int bcol_e = colg * 32 + ch_e * 16 + m;
    const int a1 = rs_e * 4 + ch_e * 2;        // accumulator pair base

    f32x4 zx4 = *(const f32x4*)(zxv + h04);
    f32x4 zu4 = *(const f32x4*)(zuv + h04);
    f32x4 Uc4 = *(const f32x4*)(Ucv + h04);
    f32x4 gz4 = *(const f32x4*)(g_z + h04);
    f32x4 br4 = *(const f32x4*)(b_r + h04);

    f32x4 vr, Xr, Ur;
#pragma unroll
    for (int e = 0; e < 4; ++e) {
        vr[e] = 0.0f;
        float Xn = zx4[e] + (1.0f - zx4[e]) - 0.45f;
        float Un = Uc4[e] * zu4[e] + (1.0f - zu4[e]) * 0.9f + Uc4[e] * 0.05f;
        Un = fminf(fmaxf(Un, Uc4[e]), 1.0f);
        Xr[e] = Xn; Ur[e] = Un;
    }

    __shared__ f32x4 red[4][8][64];   // [kq][acc][lane] = 32 KB

    // ---- prologue: prefetch x-operands for t=0 into registers ----
    short8 xb0[4], xb1[4];
    {
        const unsigned short* xp0 = xT + (size_t)bcol0 * INs + kx + q * 8;
        const unsigned short* xp1 = xT + (size_t)bcol1 * INs + kx + q * 8;
#pragma unroll
        for (int c = 0; c < 4; ++c) {
            xb0[c] = *(const short8*)(xp0 + c * 32);
            xb1[c] = *(const short8*)(xp1 + c * 32);
        }
    }

    for (int t = 0; t < Tt; ++t) {
        const unsigned short* Rt = (t & 1) ? Rb1 : Rb0;
        const unsigned short* Mt = (t & 1) ? Mb1 : Mb0;
        unsigned short* Rn = (t & 1) ? Rb0 : Rb1;
        unsigned short* Mn = (t & 1) ? Mb0 : Mb1;

        // acc[rowset][colhalf][mat]
        f32x4 acc[2][2][2];
#pragma unroll
        for (int rs = 0; rs < 2; ++rs)
#pragma unroll
            for (int ch = 0; ch < 2; ++ch)
#pragma unroll
                for (int mt = 0; mt < 2; ++mt)
                    acc[rs][ch][mt] = (f32x4){0.0f, 0.0f, 0.0f, 0.0f};

        // ---- x-projection: register-only MFMAs (operands prefetched) ----
#pragma unroll
        for (int c = 0; c < 4; ++c) {
#pragma unroll
            for (int rs = 0; rs < 2; ++rs) {
                acc[rs][0][0] = __builtin_amdgcn_mfma_f32_16x16x32_bf16(wf1[rs][8 + c], xb0[c], acc[rs][0][0], 0, 0, 0);
                acc[rs][1][0] = __builtin_amdgcn_mfma_f32_16x16x32_bf16(wf1[rs][8 + c], xb1[c], acc[rs][1][0], 0, 0, 0);
                acc[rs][0][1] = __builtin_amdgcn_mfma_f32_16x16x32_bf16(wf2[rs][8 + c], xb0[c], acc[rs][0][1], 0, 0, 0);
                acc[rs][1][1] = __builtin_amdgcn_mfma_f32_16x16x32_bf16(wf2[rs][8 + c], xb1[c], acc[rs][1][1], 0, 0, 0);
            }
        }

        // ---- prefetch x-operands for t+1 (cold HBM — hides under the
        //      recurrent phase; drained by the post-reduction barrier) ----
        if (t + 1 < Tt) {
            const unsigned short* xn0 = xT + (size_t)(t + 1) * Bb * INs
                                      + (size_t)bcol0 * INs + kx + q * 8;
            const unsigned short* xn1 = xT + (size_t)(t + 1) * Bb * INs
                                      + (size_t)bcol1 * INs + kx + q * 8;
#pragma unroll
            for (int c = 0; c < 4; ++c) {
                xb0[c] = *(const short8*)(xn0 + c * 32);
                xb1[c] = *(const short8*)(xn1 + c * 32);
            }
        }

        // ---- recurrent quarter: disjoint per-wave B streams (no dup) ----
        const unsigned short* rp0 = Rt + (size_t)bcol0 * Hh + krec + q * 8;
        const unsigned short* rp1 = Rt + (size_t)bcol1 * Hh + krec + q * 8;
        const unsigned short* mp0 = Mt + (size_t)bcol0 * Hh + krec + q * 8;
        const unsigned short* mp1 = Mt + (size_t)bcol1 * Hh + krec + q * 8;

#pragma unroll
        for (int c = 0; c < 8; ++c) {
            short8 bR0 = *(const short8*)(rp0 + c * 32);
            short8 bR1 = *(const short8*)(rp1 + c * 32);
            short8 bM0 = *(const short8*)(mp0 + c * 32);
            short8 bM1 = *(const short8*)(mp1 + c * 32);
#pragma unroll
            for (int rs = 0; rs < 2; ++rs) {
                acc[rs][0][0] = __builtin_amdgcn_mfma_f32_16x16x32_bf16(wf1[rs][c], bR0, acc[rs][0][0], 0, 0, 0);
                acc[rs][1][0] = __builtin_amdgcn_mfma_f32_16x16x32_bf16(wf1[rs][c], bR1, acc[rs][1][0], 0, 0, 0);
                acc[rs][0][1] = __builtin_amdgcn_mfma_f32_16x16x32_bf16(wf2[rs][c], bM0, acc[rs][0][1], 0, 0, 0);
                acc[rs][1][1] = __builtin_amdgcn_mfma_f32_16x16x32_bf16(wf2[rs][c], bM1, acc[rs][1][1], 0, 0, 0);
            }
        }

        // ---- cross-wave K reduction in LDS ----
#pragma unroll
        for (int rs = 0; rs < 2; ++rs)
#pragma unroll
            for (int ch = 0; ch < 2; ++ch)
#pragma unroll
                for (int mt = 0; mt < 2; ++mt)
                    red[kq][rs * 4 + ch * 2 + mt][lane] = acc[rs][ch][mt];
        __syncthreads();

        // ---- epilogue: each wave owns one 16x16 quadrant (4 outs/lane) ----
        f32x4 g1 = red[0][a1][lane];
        g1 += red[1][a1][lane];
        g1 += red[2][a1][lane];
        g1 += red[3][a1][lane];
        f32x4 g2 = red[0][a1 + 1][lane];
        g2 += red[1][a1 + 1][lane];
        g2 += red[2][a1 + 1][lane];
        g2 += red[3][a1 + 1][lane];

        {
            f32x4 vv;
            ushort4 rq, mq;
#pragma unroll
            for (int e = 0; e < 4; ++e) {
                float z = DT_ * sigmoidf_(g1[e] + gz4[e]);
                float vnew = (1.0f - z) * vr[e] + DT_ * (g2[e] + br4[e]);
                vr[e] = vnew;
                vv[e] = vnew;
                float r = sigmoidf_(vnew);
                float Xs = Xr[e], Us = Ur[e];
                float Xn = zx4[e] + (1.0f - zx4[e]) * Xs - Us * Xs * r;
                float Un = Uc4[e] * zu4[e] + (1.0f - zu4[e]) * Us
                         + Uc4[e] * (1.0f - Us) * r;
                Un = fminf(fmaxf(Un, Uc4[e]), 1.0f);
                Xr[e] = Xn; Ur[e] = Un;
                unsigned short rb = f2bf(r), mb = f2bf(Un * Xn * r);
                if (e == 0) { rq.x = rb; mq.x = mb; }
                else if (e == 1) { rq.y = rb; mq.y = mb; }
                else if (e == 2) { rq.z = rb; mq.z = mb; }
                else { rq.w = rb; mq.w = mb; }
            }
            const size_t base = (size_t)bcol_e * Hh + h04;
            *(f32x4*)(out + (size_t)t * Bb * Hh + base) = vv;
            *(ushort4*)(Rn + base) = rq;
            *(ushort4*)(Mn + base) = mq;
        }
        __syncthreads();   // per-wave vmcnt(0) drain -> all state stores of
                           // this block visible in this XCD's L2

        if (t + 1 < Tt) {
            // ---- arrive: relaxed monotonic add, no cache maintenance ----
            if (tid == 0)
                __hip_atomic_fetch_add(cnt, 1u, __ATOMIC_RELAXED,
                                       __HIP_MEMORY_SCOPE_AGENT);
            // ---- wait: all 32 same-colg peers (same XCD) arrived ----
            if (tid == 0) {
                const unsigned tgt = (unsigned)(t + 1) * 32u;
                while (__hip_atomic_load(cnt, __ATOMIC_RELAXED,
                                         __HIP_MEMORY_SCOPE_AGENT) < tgt)
                    __builtin_amdgcn_s_sleep(1);
                // L1-only flash invalidate: peers' fresh R/M is in our shared
                // L2; drop stale per-CU L1 lines. NOT a full-L2 walk.
                asm volatile("buffer_inv sc0" ::: "memory");
            }
            __syncthreads();
        }
    }
}

extern "C" void kernel_launch(void* const* d_in, const int* in_sizes, int n_in,
                              void* d_out, int out_size, void* d_ws, size_t ws_size,
                              hipStream_t stream) {
    const float* x   = (const float*)d_in[0];
    const float* c_x = (const float*)d_in[1];
    const float* c_u = (const float*)d_in[2];
    const float* c_U = (const float*)d_in[3];
    const float* w_r = (const float*)d_in[4];
    const float* p_r = (const float*)d_in[5];
    const float* b_r = (const float*)d_in[6];
    const float* g_z = (const float*)d_in[7];
    const float* Km  = (const float*)d_in[8];
    const float* p_z = (const float*)d_in[9];
    float* out = (float*)d_out;

    char* w = (char*)d_ws;
    unsigned short* W1 = (unsigned short*)w;   w += (size_t)Hh * KW * 2;
    unsigned short* W2 = (unsigned short*)w;   w += (size_t)Hh * KW * 2;
    unsigned short* xT = (unsigned short*)w;   w += (size_t)Tt * Bb * INs * 2;
    unsigned short* Rb0 = (unsigned short*)w;  w += (size_t)Bb * Hh * 2;
    unsigned short* Rb1 = (unsigned short*)w;  w += (size_t)Bb * Hh * 2;
    unsigned short* Mb0 = (unsigned short*)w;  w += (size_t)Bb * Hh * 2;
    unsigned short* Mb1 = (unsigned short*)w;  w += (size_t)Bb * Hh * 2;
    float* zxv = (float*)w;                    w += 4096;
    float* zuv = (float*)w;                    w += 4096;
    float* Ucv = (float*)w;                    w += 4096;
    unsigned* bar = (unsigned*)w;              w += 4096;

    build_weights<<<(Hh * KW) / 256, 256, 0, stream>>>(Km, p_z, w_r, p_r, W1, W2);
    transpose_x<<<dim3(Bb / 64, INs / 64, Tt), 256, 0, stream>>>(x, xT);
    precomp_gates<<<Hh / 256, 256, 0, stream>>>(c_x, c_u, c_U, zxv, zuv, Ucv);
    init_state<<<(Bb * Hh) / 256, 256, 0, stream>>>(zxv, zuv, Ucv, Rb0, Mb0, bar);

    persist_kernel<<<NB, 256, 0, stream>>>(
        W1, W2, xT, Rb0, Rb1, Mb0, Mb1, out,
        g_z, b_r, zxv, zuv, Ucv, bar);
}

// Round 4
// 1883.645 us; speedup vs baseline: 4.1078x; 1.0700x over previous
//
#include <hip/hip_runtime.h>
#include <hip/hip_bf16.h>

#define Hh 1024
#define INs 512
#define Bb 256
#define Tt 256
#define DT_ 0.1f
#define Z_MIN_ 0.001f
#define Z_MAX_ 0.1f
#define KW (Hh + INs)   // 1536 combined K
#define NB 256          // persistent grid = 1 block per CU

typedef __attribute__((ext_vector_type(8))) short short8;
typedef __attribute__((ext_vector_type(4))) float f32x4;
typedef __attribute__((ext_vector_type(2))) float f32x2;

__device__ __forceinline__ float sigmoidf_(float x) {
    return 1.0f / (1.0f + __expf(-x));
}

__device__ __forceinline__ unsigned short f2bf(float f) {
    union { float f; unsigned u; } v; v.f = f;
    unsigned r = v.u + 0x7FFFu + ((v.u >> 16) & 1u);  // RNE
    return (unsigned short)(r >> 16);
}

// ---- build W1=[K|p_z], W2=[w_r|p_r] as bf16 row-major 1024 x 1536 ----
__global__ __launch_bounds__(256) void build_weights(
    const float* __restrict__ Km, const float* __restrict__ p_z,
    const float* __restrict__ w_r, const float* __restrict__ p_r,
    unsigned short* __restrict__ W1, unsigned short* __restrict__ W2) {
    int idx = blockIdx.x * 256 + threadIdx.x;
    int h = idx / KW, k = idx % KW;
    float a = (k < Hh) ? Km[h * Hh + k] : p_z[h * INs + (k - Hh)];
    float b = (k < Hh) ? w_r[h * Hh + k] : p_r[h * INs + (k - Hh)];
    W1[idx] = f2bf(a);
    W2[idx] = f2bf(b);
}

// ---- x (T, IN, B) fp32 -> xT (T, B, IN) bf16 ----
__global__ __launch_bounds__(256) void transpose_x(
    const float* __restrict__ x, unsigned short* __restrict__ xT) {
    __shared__ unsigned short tile[64][65];
    int t = blockIdx.z;
    int i0 = blockIdx.y * 64;
    int b0 = blockIdx.x * 64;
    int c = threadIdx.x & 63, rbase = threadIdx.x >> 6;
    const float* xp = x + (size_t)t * INs * Bb;
#pragma unroll
    for (int r = 0; r < 16; ++r) {
        int row = r * 4 + rbase;
        tile[row][c] = f2bf(xp[(size_t)(i0 + row) * Bb + (b0 + c)]);
    }
    __syncthreads();
    unsigned short* op = xT + (size_t)t * Bb * INs;
#pragma unroll
    for (int r = 0; r < 16; ++r) {
        int brow = r * 4 + rbase;
        op[(size_t)(b0 + brow) * INs + (i0 + c)] = tile[c][brow];
    }
}

// ---- gate-rate constants (H each) ----
__global__ __launch_bounds__(256) void precomp_gates(
    const float* __restrict__ c_x, const float* __restrict__ c_u,
    const float* __restrict__ c_U,
    float* __restrict__ zxv, float* __restrict__ zuv, float* __restrict__ Ucv) {
    int h = blockIdx.x * 256 + threadIdx.x;
    zxv[h] = Z_MIN_ + (Z_MAX_ - Z_MIN_) * sigmoidf_(c_x[h]);
    zuv[h] = Z_MIN_ + (Z_MAX_ - Z_MIN_) * sigmoidf_(c_u[h]);
    Ucv[h] = 0.9f * sigmoidf_(c_U[h]);
}

// ---- initial R_0, M_0 (B,H) bf16 ; also zero the 16 per-colg barrier words --
__global__ __launch_bounds__(256) void init_state(
    const float* __restrict__ zxv, const float* __restrict__ zuv,
    const float* __restrict__ Ucv,
    unsigned short* __restrict__ R0, unsigned short* __restrict__ M0,
    unsigned* __restrict__ bar) {
    int idx = blockIdx.x * 256 + threadIdx.x;           // over B*H
    if (idx < 16) bar[idx * 32] = 0;                    // 16 counters, 128B apart
    int h = idx & (Hh - 1);
    float zx = zxv[h], zu = zuv[h], Uc = Ucv[h];
    const float r = 0.5f;                                // sigmoid(0)
    float Xn = zx + (1.0f - zx) - 0.45f;                 // X0=1,U0=0.9
    float Un = Uc * zu + (1.0f - zu) * 0.9f + Uc * 0.05f;
    Un = fminf(fmaxf(Un, Uc), 1.0f);
    R0[idx] = f2bf(r);
    M0[idx] = f2bf(Un * Xn * r);
}

// ---- persistent kernel: all 256 timesteps ----
// R4 restructure: 512 threads (8 waves, 2/SIMD), output tile 64 rows x 16 cols
// (16 rowg x 16 colg = 256 blocks). Waves are an 8-way K-split (kq = wave:
// recurrent [kq*128,+128) + x [kq*64,+64)), each covering all 64 rows via 4
// A-fragment rowsets. Same per-lane weight budget as R3 (4rs x 6ch x 2 mats =
// 48 short8 = 192 regs), but per-block B-operand state volume HALVES
// (16 cols x 1024 x 2 arrays x 2B = 64 KB/step) — B volume scales with cols
// only, so the tall-narrow tile amortizes it over 2x rows. 2 waves/SIMD also
// finally hides load latency (R3 ran 1 wave/SIMD, fully exposed).
// Epilogue spread over all 8 waves: wave = (rs_e, eh), 2 outputs/lane.
//
// SYNC (protocol unchanged, groups re-keyed): state exchange is intra-XCD —
// blocks with blockIdx%16 == colg are all == colg (mod 8) -> same XCD. 16
// per-colg counters, 16 blocks each; stores drain to the shared L2 at the
// pre-barrier vmcnt(0); relaxed agent atomics + per-CU L1-only invalidate
// (buffer_inv sc0). No agent-scope L2 walks.
__global__ __launch_bounds__(512, 1) void persist_kernel(
    const unsigned short* __restrict__ W1, const unsigned short* __restrict__ W2,
    const unsigned short* __restrict__ xT,
    unsigned short* __restrict__ Rb0, unsigned short* __restrict__ Rb1,
    unsigned short* __restrict__ Mb0, unsigned short* __restrict__ Mb1,
    float* __restrict__ out,
    const float* __restrict__ g_z, const float* __restrict__ b_r,
    const float* __restrict__ zxv, const float* __restrict__ zuv,
    const float* __restrict__ Ucv, unsigned* __restrict__ bar) {

    const int tid = threadIdx.x;
    const int wave = tid >> 6, lane = tid & 63;
    const int m = lane & 15, q = lane >> 4;
    const int kq = wave;               // 0..7: K eighth
    const int rowg = blockIdx.x >> 4;  // 16 row groups (64 rows each)
    const int colg = blockIdx.x & 15;  // 16 col groups (16 cols) — XCD-aligned

    unsigned* cnt = bar + (unsigned)colg * 32;   // per-colg counter, 128B apart

    const int krec = kq * 128;                 // recurrent K base (eighth)
    const int kx = kq * 64;                    // x-proj K base (eighth of IN)
    const int bcol = colg * 16 + m;

    // ---- pin weights: 4 rowsets x (4 rec + 2 x) chunks x 2 matrices ----
    short8 wf1[4][6], wf2[4][6];
#pragma unroll
    for (int rs = 0; rs < 4; ++rs) {
        const int arow = rowg * 64 + rs * 16 + m;
        const unsigned short* w1r = W1 + (size_t)arow * KW + krec + q * 8;
        const unsigned short* w2r = W2 + (size_t)arow * KW + krec + q * 8;
#pragma unroll
        for (int c = 0; c < 4; ++c) {
            wf1[rs][c] = *(const short8*)(w1r + c * 32);
            wf2[rs][c] = *(const short8*)(w2r + c * 32);
        }
        const unsigned short* w1x = W1 + (size_t)arow * KW + Hh + kx + q * 8;
        const unsigned short* w2x = W2 + (size_t)arow * KW + Hh + kx + q * 8;
#pragma unroll
        for (int c = 0; c < 2; ++c) {
            wf1[rs][4 + c] = *(const short8*)(w1x + c * 32);
            wf2[rs][4 + c] = *(const short8*)(w2x + c * 32);
        }
    }

    // ---- epilogue assignment: wave -> (rowset, element half); 2 outs/lane --
    const int rs_e = wave >> 1, eh = wave & 1;
    const int h2 = rowg * 64 + rs_e * 16 + q * 4 + eh * 2;
    const int bcol_e = colg * 16 + m;

    f32x2 zx2 = *(const f32x2*)(zxv + h2);
    f32x2 zu2 = *(const f32x2*)(zuv + h2);
    f32x2 Uc2 = *(const f32x2*)(Ucv + h2);
    f32x2 gz2 = *(const f32x2*)(g_z + h2);
    f32x2 br2 = *(const f32x2*)(b_r + h2);

    f32x2 vr, Xr, Ur;
#pragma unroll
    for (int j = 0; j < 2; ++j) {
        vr[j] = 0.0f;
        float Xn = zx2[j] + (1.0f - zx2[j]) - 0.45f;
        float Un = Uc2[j] * zu2[j] + (1.0f - zu2[j]) * 0.9f + Uc2[j] * 0.05f;
        Un = fminf(fmaxf(Un, Uc2[j]), 1.0f);
        Xr[j] = Xn; Ur[j] = Un;
    }

    __shared__ f32x4 red[8][4][2][64];   // [kq][rs][mat][lane] = 64 KB

    // ---- prologue: prefetch x-operands for t=0 into registers ----
    short8 xb[2];
    {
        const unsigned short* xp = xT + (size_t)bcol * INs + kx + q * 8;
#pragma unroll
        for (int c = 0; c < 2; ++c)
            xb[c] = *(const short8*)(xp + c * 32);
    }

    for (int t = 0; t < Tt; ++t) {
        const unsigned short* Rt = (t & 1) ? Rb1 : Rb0;
        const unsigned short* Mt = (t & 1) ? Mb1 : Mb0;
        unsigned short* Rn = (t & 1) ? Rb0 : Rb1;
        unsigned short* Mn = (t & 1) ? Mb0 : Mb1;

        // acc[rowset][mat]
        f32x4 acc[4][2];
#pragma unroll
        for (int rs = 0; rs < 4; ++rs)
#pragma unroll
            for (int mt = 0; mt < 2; ++mt)
                acc[rs][mt] = (f32x4){0.0f, 0.0f, 0.0f, 0.0f};

        // ---- x-projection: register-only MFMAs (operands prefetched) ----
#pragma unroll
        for (int c = 0; c < 2; ++c)
#pragma unroll
            for (int rs = 0; rs < 4; ++rs) {
                acc[rs][0] = __builtin_amdgcn_mfma_f32_16x16x32_bf16(wf1[rs][4 + c], xb[c], acc[rs][0], 0, 0, 0);
                acc[rs][1] = __builtin_amdgcn_mfma_f32_16x16x32_bf16(wf2[rs][4 + c], xb[c], acc[rs][1], 0, 0, 0);
            }

        // ---- prefetch x-operands for t+1 (hides under recurrent phase;
        //      drained by the post-reduction barrier) ----
        if (t + 1 < Tt) {
            const unsigned short* xn = xT + (size_t)(t + 1) * Bb * INs
                                     + (size_t)bcol * INs + kx + q * 8;
#pragma unroll
            for (int c = 0; c < 2; ++c)
                xb[c] = *(const short8*)(xn + c * 32);
        }

        // ---- recurrent eighth: disjoint per-wave B streams ----
        const unsigned short* rp = Rt + (size_t)bcol * Hh + krec + q * 8;
        const unsigned short* mp = Mt + (size_t)bcol * Hh + krec + q * 8;

#pragma unroll
        for (int c = 0; c < 4; ++c) {
            short8 bR = *(const short8*)(rp + c * 32);
            short8 bM = *(const short8*)(mp + c * 32);
#pragma unroll
            for (int rs = 0; rs < 4; ++rs) {
                acc[rs][0] = __builtin_amdgcn_mfma_f32_16x16x32_bf16(wf1[rs][c], bR, acc[rs][0], 0, 0, 0);
                acc[rs][1] = __builtin_amdgcn_mfma_f32_16x16x32_bf16(wf2[rs][c], bM, acc[rs][1], 0, 0, 0);
            }
        }

        // ---- cross-wave K reduction in LDS ----
#pragma unroll
        for (int rs = 0; rs < 4; ++rs)
#pragma unroll
            for (int mt = 0; mt < 2; ++mt)
                red[kq][rs][mt][lane] = acc[rs][mt];
        __syncthreads();

        // ---- epilogue: all 8 waves; this wave owns (rs_e, eh) ----
        {
            f32x2 g1 = {0.0f, 0.0f}, g2 = {0.0f, 0.0f};
#pragma unroll
            for (int k2 = 0; k2 < 8; ++k2) {
                const float* p1 = (const float*)&red[k2][rs_e][0][lane];
                const float* p2 = (const float*)&red[k2][rs_e][1][lane];
                g1 += *(const f32x2*)(p1 + eh * 2);
                g2 += *(const f32x2*)(p2 + eh * 2);
            }

            f32x2 vv;
            ushort2 rq, mq;
#pragma unroll
            for (int j = 0; j < 2; ++j) {
                float z = DT_ * sigmoidf_(g1[j] + gz2[j]);
                float vnew = (1.0f - z) * vr[j] + DT_ * (g2[j] + br2[j]);
                vr[j] = vnew;
                vv[j] = vnew;
                float r = sigmoidf_(vnew);
                float Xs = Xr[j], Us = Ur[j];
                float Xn = zx2[j] + (1.0f - zx2[j]) * Xs - Us * Xs * r;
                float Un = Uc2[j] * zu2[j] + (1.0f - zu2[j]) * Us
                         + Uc2[j] * (1.0f - Us) * r;
                Un = fminf(fmaxf(Un, Uc2[j]), 1.0f);
                Xr[j] = Xn; Ur[j] = Un;
                unsigned short rb = f2bf(r), mb = f2bf(Un * Xn * r);
                if (j == 0) { rq.x = rb; mq.x = mb; }
                else        { rq.y = rb; mq.y = mb; }
            }
            const size_t base = (size_t)bcol_e * Hh + h2;
            *(f32x2*)(out + (size_t)t * Bb * Hh + base) = vv;
            *(ushort2*)(Rn + base) = rq;
            *(ushort2*)(Mn + base) = mq;
        }
        __syncthreads();   // per-wave vmcnt(0) drain -> all state stores of
                           // this block visible in this XCD's L2

        if (t + 1 < Tt) {
            // ---- arrive: relaxed monotonic add, no cache maintenance ----
            if (tid == 0)
                __hip_atomic_fetch_add(cnt, 1u, __ATOMIC_RELAXED,
                                       __HIP_MEMORY_SCOPE_AGENT);
            // ---- wait: all 16 same-colg peers (same XCD) arrived ----
            if (tid == 0) {
                const unsigned tgt = (unsigned)(t + 1) * 16u;
                while (__hip_atomic_load(cnt, __ATOMIC_RELAXED,
                                         __HIP_MEMORY_SCOPE_AGENT) < tgt)
                    __builtin_amdgcn_s_sleep(1);
                // L1-only flash invalidate: peers' fresh R/M is in our shared
                // L2; drop stale per-CU L1 lines. NOT a full-L2 walk.
                asm volatile("buffer_inv sc0" ::: "memory");
            }
            __syncthreads();
        }
    }
}

extern "C" void kernel_launch(void* const* d_in, const int* in_sizes, int n_in,
                              void* d_out, int out_size, void* d_ws, size_t ws_size,
                              hipStream_t stream) {
    const float* x   = (const float*)d_in[0];
    const float* c_x = (const float*)d_in[1];
    const float* c_u = (const float*)d_in[2];
    const float* c_U = (const float*)d_in[3];
    const float* w_r = (const float*)d_in[4];
    const float* p_r = (const float*)d_in[5];
    const float* b_r = (const float*)d_in[6];
    const float* g_z = (const float*)d_in[7];
    const float* Km  = (const float*)d_in[8];
    const float* p_z = (const float*)d_in[9];
    float* out = (float*)d_out;

    char* w = (char*)d_ws;
    unsigned short* W1 = (unsigned short*)w;   w += (size_t)Hh * KW * 2;
    unsigned short* W2 = (unsigned short*)w;   w += (size_t)Hh * KW * 2;
    unsigned short* xT = (unsigned short*)w;   w += (size_t)Tt * Bb * INs * 2;
    unsigned short* Rb0 = (unsigned short*)w;  w += (size_t)Bb * Hh * 2;
    unsigned short* Rb1 = (unsigned short*)w;  w += (size_t)Bb * Hh * 2;
    unsigned short* Mb0 = (unsigned short*)w;  w += (size_t)Bb * Hh * 2;
    unsigned short* Mb1 = (unsigned short*)w;  w += (size_t)Bb * Hh * 2;
    float* zxv = (float*)w;                    w += 4096;
    float* zuv = (float*)w;                    w += 4096;
    float* Ucv = (float*)w;                    w += 4096;
    unsigned* bar = (unsigned*)w;              w += 4096;

    build_weights<<<(Hh * KW) / 256, 256, 0, stream>>>(Km, p_z, w_r, p_r, W1, W2);
    transpose_x<<<dim3(Bb / 64, INs / 64, Tt), 256, 0, stream>>>(x, xT);
    precomp_gates<<<Hh / 256, 256, 0, stream>>>(c_x, c_u, c_U, zxv, zuv, Ucv);
    init_state<<<(Bb * Hh) / 256, 256, 0, stream>>>(zxv, zuv, Ucv, Rb0, Mb0, bar);

    persist_kernel<<<NB, 512, 0, stream>>>(
        W1, W2, xT, Rb0, Rb1, Mb0, Mb1, out,
        g_z, b_r, zxv, zuv, Ucv, bar);
}